// Round 2
// baseline (653.152 us; speedup 1.0000x reference)
//
#include <hip/hip_runtime.h>

// SynthesisLayer: modulated conv2d 3x3 + demod + noise + bias + lrelu*sqrt(2)
// B=16, CIN=COUT=512, RES=64, WDIM=512

#define NB   16
#define NCI  512
#define NCO  512
#define NRES 64
#define NWD  512

typedef __attribute__((ext_vector_type(8))) short short8;
typedef __attribute__((ext_vector_type(4))) float f32x4;

static __device__ __forceinline__ unsigned short f2bf(float f) {
  unsigned int u = __float_as_uint(f);
  u += 0x7fffu + ((u >> 16) & 1u);   // RNE
  return (unsigned short)(u >> 16);
}

// ---------------- PK1: styles[b][ci] = m1*m2 + m3 ----------------
__global__ __launch_bounds__(512) void k_styles(
    const float* __restrict__ w, const float* __restrict__ aw,
    const float* __restrict__ ab, float* __restrict__ styles) {
  const int b = blockIdx.x, j = threadIdx.x;
  __shared__ float ws[NWD];
  ws[j] = w[b * NWD + j];
  __syncthreads();
  const float4* wv = (const float4*)ws;
  const float4* r0 = (const float4*)(aw + (size_t)j * NWD);
  const float4* r1 = (const float4*)(aw + (size_t)(j + 512) * NWD);
  const float4* r2 = (const float4*)(aw + (size_t)(j + 1024) * NWD);
  float a0 = 0.f, a1 = 0.f, a2 = 0.f;
  for (int k = 0; k < NWD / 4; ++k) {
    float4 x = wv[k];
    float4 y0 = r0[k], y1 = r1[k], y2 = r2[k];
    a0 += x.x * y0.x + x.y * y0.y + x.z * y0.z + x.w * y0.w;
    a1 += x.x * y1.x + x.y * y1.y + x.z * y1.z + x.w * y1.w;
    a2 += x.x * y2.x + x.y * y2.y + x.z * y2.z + x.w * y2.w;
  }
  const float g = 0.04419417382415922f;  // 1/sqrt(512)
  float m1 = a0 * g + ab[j];
  float m2 = a1 * g + ab[j + 512];
  float m3 = a2 * g + ab[j + 1024];
  styles[b * NWD + j] = m1 * m2 + m3;
}

// ---------------- PK2: weight -> bf16 wb[khkw][co][ci], wsq[co][ci] ----------------
__global__ __launch_bounds__(256) void k_wt(
    const float* __restrict__ wgt, short* __restrict__ wb, float* __restrict__ wsq) {
  const int t = blockIdx.x * 256 + threadIdx.x;  // 0..262143 = co*512+ci
  const int co = t >> 9, ci = t & 511;
  const float* p = wgt + (size_t)t * 9;
  float s = 0.f;
#pragma unroll
  for (int kk = 0; kk < 9; ++kk) {
    float v = p[kk];
    s += v * v;
    wb[((size_t)kk * NCO + co) * NCI + ci] = (short)f2bf(v);
  }
  wsq[t] = s;
}

// ---------------- PK3: dcoef[b][co] = rsqrt(sum_ci wsq*s^2 + 1e-8) ----------------
__global__ __launch_bounds__(256) void k_dcoef(
    const float* __restrict__ wsq, const float* __restrict__ styles,
    float* __restrict__ dcoef) {
  const int t = blockIdx.x * 256 + threadIdx.x;  // 0..8191 = b*512+co
  const int b = t >> 9, co = t & 511;
  const float4* q = (const float4*)(wsq + (size_t)co * NCI);
  const float4* s = (const float4*)(styles + (size_t)b * NCI);
  float acc = 0.f;
  for (int k = 0; k < NCI / 4; ++k) {
    float4 a = q[k], sv = s[k];
    acc += a.x * sv.x * sv.x + a.y * sv.y * sv.y + a.z * sv.z * sv.z + a.w * sv.w * sv.w;
  }
  dcoef[t] = 1.0f / sqrtf(acc + 1e-8f);
}

// ---------------- PK4: xt[b][h][w][ci] = bf16(x[b][ci][h][w] * styles[b][ci]) ----------------
__global__ __launch_bounds__(256) void k_xt(
    const float* __restrict__ x, const float* __restrict__ styles,
    short* __restrict__ xt) {
  const int px0 = blockIdx.x * 64;   // 64 pixels (flat h*64+w)
  const int ci0 = blockIdx.y * 32;
  const int b = blockIdx.z;
  __shared__ float tile[32][65];
  const int t = threadIdx.x;
#pragma unroll
  for (int k = 0; k < 8; ++k) {
    int idx = t + k * 256;
    int cil = idx >> 6, pxl = idx & 63;
    tile[cil][pxl] = x[((size_t)(b * NCI + ci0 + cil)) * 4096 + px0 + pxl];
  }
  __syncthreads();
#pragma unroll
  for (int k = 0; k < 8; ++k) {
    int idx = t + k * 256;
    int pxl = idx >> 5, cil = idx & 31;
    float v = tile[cil][pxl] * styles[b * NCI + ci0 + cil];
    xt[((size_t)b * 4096 + px0 + pxl) * NCI + ci0 + cil] = (short)f2bf(v);
  }
}

// ---------------- conv: implicit GEMM, 64co x (4 rows x 64 w) per block ----------------
__global__ __launch_bounds__(256, 2) void k_conv(
    const short* __restrict__ xt, const short* __restrict__ wb,
    const float* __restrict__ dcoef, const float* __restrict__ bias,
    const float* __restrict__ noise, const float* __restrict__ nstr,
    float* __restrict__ out) {
  const int co0 = blockIdx.x * 64;
  const int h0 = blockIdx.y * 4;
  const int b = blockIdx.z;
  __shared__ short xs[6][66][32];   // [row][1+w (halo cols 0,65)][ci]
  __shared__ short wls[9][64][32];  // [khkw][co][ci]
  const int t = threadIdx.x;
  const int lane = t & 63, wave = t >> 6;
  const int lrow = lane & 15, lq = lane >> 4;
  const int wq = t >> 2, cq = t & 3;

  // zero halo columns once (re-used every K-step): 6 rows x 2 sides x 32 ci = 384
  for (int i = t; i < 384; i += 256) {
    int r = i >> 6, side = (i >> 5) & 1, c = i & 31;
    xs[r][side ? 65 : 0][c] = 0;
  }

  f32x4 acc[4][4];
#pragma unroll
  for (int m = 0; m < 4; ++m)
#pragma unroll
    for (int n = 0; n < 4; ++n)
#pragma unroll
      for (int e = 0; e < 4; ++e) acc[m][n][e] = 0.f;

  const size_t xb_base = (size_t)b * 64 * 64 * NCI;

  for (int ci0 = 0; ci0 < NCI; ci0 += 32) {
    // ---- stage x rows h0-1 .. h0+4 ----
#pragma unroll
    for (int r = 0; r < 6; ++r) {
      int row = h0 - 1 + r;
      short8 v;
      if ((unsigned)row < 64u) {
        v = *(const short8*)(xt + xb_base + ((size_t)row * 64 + wq) * NCI + ci0 + cq * 8);
      } else {
#pragma unroll
        for (int i = 0; i < 8; ++i) v[i] = 0;
      }
      *(short8*)(&xs[r][1 + wq][cq * 8]) = v;
    }
    // ---- stage weights ----
#pragma unroll
    for (int kk = 0; kk < 9; ++kk) {
      short8 v = *(const short8*)(wb + ((size_t)kk * NCO + co0 + wq) * NCI + ci0 + cq * 8);
      *(short8*)(&wls[kk][wq][cq * 8]) = v;
    }
    __syncthreads();

#pragma unroll
    for (int kh = 0; kh < 3; ++kh) {
#pragma unroll
      for (int kw = 0; kw < 3; ++kw) {
        short8 af[4], bf[4];
#pragma unroll
        for (int m = 0; m < 4; ++m)
          af[m] = *(const short8*)(&wls[kh * 3 + kw][m * 16 + lrow][lq * 8]);
#pragma unroll
        for (int n = 0; n < 4; ++n)
          bf[n] = *(const short8*)(&xs[wave + kh][n * 16 + lrow + kw][lq * 8]);
#pragma unroll
        for (int m = 0; m < 4; ++m)
#pragma unroll
          for (int n = 0; n < 4; ++n)
            acc[m][n] = __builtin_amdgcn_mfma_f32_16x16x32_bf16(af[m], bf[n], acc[m][n], 0, 0, 0);
      }
    }
    __syncthreads();
  }

  // ---- epilogue: demod, noise, bias, lrelu*sqrt(2) ----
  const float ns = nstr[0];
  const int h = h0 + wave;
  float dc[4][4], bv[4][4];
#pragma unroll
  for (int m = 0; m < 4; ++m)
#pragma unroll
    for (int r = 0; r < 4; ++r) {
      int co = co0 + m * 16 + lq * 4 + r;
      dc[m][r] = dcoef[b * NCO + co];
      bv[m][r] = bias[co];
    }
#pragma unroll
  for (int n = 0; n < 4; ++n) {
    int wcol = n * 16 + lrow;
    float nz = noise[h * 64 + wcol] * ns;
#pragma unroll
    for (int m = 0; m < 4; ++m) {
#pragma unroll
      for (int r = 0; r < 4; ++r) {
        int co = co0 + m * 16 + lq * 4 + r;
        float v = acc[m][n][r] * dc[m][r] + nz + bv[m][r];
        v = (v > 0.f ? v : 0.2f * v) * 1.4142135623730951f;
        out[(((size_t)b * NCO + co) * 64 + h) * 64 + wcol] = v;
      }
    }
  }
}

extern "C" void kernel_launch(void* const* d_in, const int* in_sizes, int n_in,
                              void* d_out, int out_size, void* d_ws, size_t ws_size,
                              hipStream_t stream) {
  const float* x    = (const float*)d_in[0];
  const float* w    = (const float*)d_in[1];
  const float* aw   = (const float*)d_in[2];
  const float* ab   = (const float*)d_in[3];
  const float* wgt  = (const float*)d_in[4];
  const float* bias = (const float*)d_in[5];
  const float* nc   = (const float*)d_in[6];
  const float* ns   = (const float*)d_in[7];
  float* out = (float*)d_out;

  char* ws = (char*)d_ws;
  float* styles = (float*)(ws);                 // 32 KB
  float* dcoef  = (float*)(ws + 32768);         // 32 KB
  float* wsq    = (float*)(ws + 65536);         // 1 MB
  short* wb     = (short*)(ws + 1114112);       // 4.5 MB
  short* xt     = (short*)(ws + 5832704);       // 64 MB  (total ~69.6 MB)

  k_styles<<<dim3(16), dim3(512), 0, stream>>>(w, aw, ab, styles);
  k_wt<<<dim3(1024), dim3(256), 0, stream>>>(wgt, wb, wsq);
  k_dcoef<<<dim3(32), dim3(256), 0, stream>>>(wsq, styles, dcoef);
  k_xt<<<dim3(64, 16, 16), dim3(256), 0, stream>>>(x, styles, xt);
  k_conv<<<dim3(8, 16, 16), dim3(256), 0, stream>>>(xt, wb, dcoef, bias, nc, ns, out);
}

// Round 5
// 505.938 us; speedup vs baseline: 1.2910x; 1.2910x over previous
//
#include <hip/hip_runtime.h>

// SynthesisLayer: modulated conv2d 3x3 + demod + noise + bias + lrelu*sqrt(2)
// B=16, CIN=COUT=512, RES=64, WDIM=512

#define NCI  512
#define NCO  512

typedef __attribute__((ext_vector_type(8))) short short8;
typedef __attribute__((ext_vector_type(4))) float f32x4;

#define GLDS16(g, l) __builtin_amdgcn_global_load_lds( \
    (const __attribute__((address_space(1))) void*)(g), \
    (__attribute__((address_space(3))) void*)(l), 16, 0, 0)

static __device__ __forceinline__ unsigned short f2bf(float f) {
  unsigned int u = __float_as_uint(f);
  u += 0x7fffu + ((u >> 16) & 1u);   // RNE
  return (unsigned short)(u >> 16);
}

// ---------------- PK1: styles[b][ci] = m1*m2 + m3 ----------------
// grid (16 ci-chunks, 16 b), 256 thr. 8 lanes per output row, shuffle-reduce.
__global__ __launch_bounds__(256) void k_styles(
    const float* __restrict__ w, const float* __restrict__ aw,
    const float* __restrict__ ab, float* __restrict__ styles) {
  const int ci0 = blockIdx.x * 32, b = blockIdx.y;
  __shared__ float ws[512];
  __shared__ float pm[3][32];
  const int t = threadIdx.x;
  ws[t] = w[b * 512 + t];
  ws[t + 256] = w[b * 512 + 256 + t];
  __syncthreads();
  const int r = t >> 3, k = t & 7;
#pragma unroll
  for (int pass = 0; pass < 3; ++pass) {
    const float* row = aw + (size_t)(ci0 + r + pass * 512) * 512;
    float a = 0.f;
#pragma unroll 4
    for (int i = 0; i < 16; ++i) {
      float4 v = *(const float4*)(row + i * 32 + k * 4);
      float4 u = *(const float4*)(&ws[i * 32 + k * 4]);
      a += v.x * u.x + v.y * u.y + v.z * u.z + v.w * u.w;
    }
    a += __shfl_xor(a, 1); a += __shfl_xor(a, 2); a += __shfl_xor(a, 4);
    if (k == 0) pm[pass][r] = a;
  }
  __syncthreads();
  if (t < 32) {
    const float g = 0.04419417382415922f;  // 1/sqrt(512)
    int j = ci0 + t;
    float m1 = pm[0][t] * g + ab[j];
    float m2 = pm[1][t] * g + ab[j + 512];
    float m3 = pm[2][t] * g + ab[j + 1024];
    styles[b * 512 + j] = m1 * m2 + m3;
  }
}

// ---------------- PK2: weight -> bf16 fragment-linear wb2, wsq[co][ci] ----------------
// wb2 layout: [ci_blk(16)][co_blk(8)][kk(9)][m(4)][lane(64)][e(8)] shorts
//   lane = ((ci>>3)&3)*16 + (co&15), m=(co>>4)&3, e=ci&7
__global__ __launch_bounds__(256) void k_wt(
    const float* __restrict__ wgt, short* __restrict__ wb2, float* __restrict__ wsq) {
  const int t = blockIdx.x * 256 + threadIdx.x;  // co*512+ci
  const int co = t >> 9, ci = t & 511;
  const float* p = wgt + (size_t)t * 9;
  const int ci_blk = ci >> 5, co_blk = co >> 6, m = (co >> 4) & 3;
  const int lane2 = ((ci >> 3) & 3) * 16 + (co & 15), e = ci & 7;
  const size_t base = (size_t)(ci_blk * 8 + co_blk) * 18432 + (size_t)m * 512 + lane2 * 8 + e;
  float s = 0.f;
#pragma unroll
  for (int kk = 0; kk < 9; ++kk) {
    float v = p[kk];
    s += v * v;
    wb2[base + (size_t)kk * 2048] = (short)f2bf(v);
  }
  wsq[t] = s;
}

// ---------------- PK3: dcoef[b][co] = rsqrt(sum_ci wsq*s^2 + 1e-8) ----------------
__global__ __launch_bounds__(256) void k_dcoef(
    const float* __restrict__ wsq, const float* __restrict__ styles,
    float* __restrict__ dcoef) {
  const int co0 = blockIdx.x * 32, b = blockIdx.y;
  __shared__ float ss[512];
  const int t = threadIdx.x;
  float s0 = styles[b * 512 + t], s1 = styles[b * 512 + 256 + t];
  ss[t] = s0 * s0;
  ss[t + 256] = s1 * s1;
  __syncthreads();
  const int r = t >> 3, k = t & 7;
  const float* row = wsq + (size_t)(co0 + r) * 512;
  float a = 0.f;
#pragma unroll 4
  for (int i = 0; i < 16; ++i) {
    float4 v = *(const float4*)(row + i * 32 + k * 4);
    float4 u = *(const float4*)(&ss[i * 32 + k * 4]);
    a += v.x * u.x + v.y * u.y + v.z * u.z + v.w * u.w;
  }
  a += __shfl_xor(a, 1); a += __shfl_xor(a, 2); a += __shfl_xor(a, 4);
  if (k == 0) dcoef[b * 512 + co0 + r] = 1.0f / sqrtf(a + 1e-8f);
}

// ---------------- PK4: xt[b][px][ci] = bf16(x[b][ci][px] * styles[b][ci]) ----------------
// grid (64 px-chunks, 16 ci-chunks, 16 b). float4 loads -> LDS -> short8 stores.
__global__ __launch_bounds__(256) void k_xt(
    const float* __restrict__ x, const float* __restrict__ styles,
    short* __restrict__ xt) {
  const int px0 = blockIdx.x * 64, ci0 = blockIdx.y * 32, b = blockIdx.z;
  __shared__ float tile[32][68];
  const int t = threadIdx.x;
  {
    const int cil = t >> 4, pxq = t & 15;
#pragma unroll
    for (int half = 0; half < 2; ++half) {
      const int c = cil + half * 16;   // cover all 32 ci rows (R3 bug: only 0..15)
      float4 v = *(const float4*)(x + ((size_t)(b * 512 + ci0 + c)) * 4096 + px0 + pxq * 4);
      float sc = styles[b * 512 + ci0 + c];
      v.x *= sc; v.y *= sc; v.z *= sc; v.w *= sc;
      *(float4*)(&tile[c][pxq * 4]) = v;
    }
  }
  __syncthreads();
  {
    const int pxl = t >> 2, cig = t & 3;
    short8 o;
#pragma unroll
    for (int e = 0; e < 8; ++e) o[e] = (short)f2bf(tile[cig * 8 + e][pxl]);
    *(short8*)(xt + ((size_t)(b * 4096 + px0 + pxl)) * 512 + ci0 + cig * 8) = o;
  }
}

// ---------------- conv: implicit GEMM, 64co x (4 rows x 64 w) per block ----------------
// LDS: xs2[6][4][66][8] (k-plane-major X tile, halo cols 0/65 zero),
//      wls2[9][4][64][8] (fragment-linear W tile). Both staged via global_load_lds.
__global__ __launch_bounds__(256, 2) void k_conv(
    const short* __restrict__ xt, const short* __restrict__ wb2,
    const float* __restrict__ dcoef, const float* __restrict__ bias,
    const float* __restrict__ noise, const float* __restrict__ nstr,
    float* __restrict__ out) {
  // XCD-aware swizzle: 2048 blocks, 8 XCDs, 256 per chunk (bijective: 2048%8==0)
  const int bid = blockIdx.x;
  const int logical = (bid & 7) * 256 + (bid >> 3);
  const int co0 = (logical & 7) * 64;
  const int h0  = ((logical >> 3) & 15) * 4;
  const int b   = logical >> 7;

  __shared__ short xs2[6][4][66][8];    // 25344 B
  __shared__ short wls2[9][4][64][8];   // 36864 B
  const int t = threadIdx.x;
  const int lane = t & 63, wave = t >> 6;
  const int lrow = lane & 15, lq = lane >> 4;

  const short8 z8 = {0, 0, 0, 0, 0, 0, 0, 0};
  // halo columns 0 and 65 of every (r, plane): 6*4*2 = 48 chunks of 16B
  if (t < 48) {
    int r = t / 8, pc = t & 7;
    *(short8*)(&xs2[r][pc >> 1][(pc & 1) ? 65 : 0][0]) = z8;
  }
  // out-of-bounds row slabs stay zero for the whole K loop (never staged)
  if (h0 == 0)
    for (int i = t; i < 264; i += 256) ((short8*)&xs2[0][0][0][0])[i] = z8;
  if (h0 == 60)
    for (int i = t; i < 264; i += 256) ((short8*)&xs2[5][0][0][0])[i] = z8;

  f32x4 acc[4][4];
#pragma unroll
  for (int m = 0; m < 4; ++m)
#pragma unroll
    for (int n = 0; n < 4; ++n)
#pragma unroll
      for (int e = 0; e < 4; ++e) acc[m][n][e] = 0.f;

  const size_t xb = (size_t)b * 4096 * 512;
  const int cob = co0 >> 6;

  for (int cb = 0; cb < 16; ++cb) {
    const int ci0 = cb * 32;
    // ---- stage X: 6 rows x 4 ci-planes, one wave-stage each (64 lanes x 16B) ----
#pragma unroll
    for (int i = 0; i < 6; ++i) {
      int rp = i * 4 + wave;           // 0..23 -> r=i, p=wave
      int r = rp >> 2, p = rp & 3;
      int row = h0 - 1 + r;
      if ((unsigned)row < 64u) {
        const short* g = xt + xb + ((size_t)(row * 64 + lane)) * 512 + ci0 + p * 8;
        GLDS16(g, &xs2[r][p][1][0]);
      }
    }
    // ---- stage W: contiguous 36864B block, 36 wave-stages ----
    const short* wbase = wb2 + (size_t)(cb * 8 + cob) * 18432;
#pragma unroll
    for (int i = 0; i < 9; ++i) {
      int c = i * 4 + wave;            // 0..35
      GLDS16(wbase + c * 512 + lane * 8, ((short*)wls2) + c * 512);
    }
    __syncthreads();

#pragma unroll
    for (int kh = 0; kh < 3; ++kh) {
#pragma unroll
      for (int kw = 0; kw < 3; ++kw) {
        const int kk = kh * 3 + kw;
        short8 af[4], bf[4];
#pragma unroll
        for (int m = 0; m < 4; ++m)
          af[m] = *(const short8*)(&wls2[kk][m][lane][0]);
#pragma unroll
        for (int n = 0; n < 4; ++n)
          bf[n] = *(const short8*)(&xs2[wave + kh][lq][n * 16 + lrow + kw][0]);
#pragma unroll
        for (int m = 0; m < 4; ++m)
#pragma unroll
          for (int n = 0; n < 4; ++n)
            acc[m][n] = __builtin_amdgcn_mfma_f32_16x16x32_bf16(af[m], bf[n], acc[m][n], 0, 0, 0);
      }
    }
    __syncthreads();
  }

  // ---- epilogue: demod, noise, bias, lrelu*sqrt(2) ----
  const float ns = nstr[0];
  const int h = h0 + wave;
  float dc[4][4], bv[4][4];
#pragma unroll
  for (int m = 0; m < 4; ++m)
#pragma unroll
    for (int r = 0; r < 4; ++r) {
      int co = co0 + m * 16 + lq * 4 + r;
      dc[m][r] = dcoef[b * NCO + co];
      bv[m][r] = bias[co];
    }
#pragma unroll
  for (int n = 0; n < 4; ++n) {
    int wcol = n * 16 + lrow;
    float nz = noise[h * 64 + wcol] * ns;
#pragma unroll
    for (int m = 0; m < 4; ++m) {
#pragma unroll
      for (int r = 0; r < 4; ++r) {
        int co = co0 + m * 16 + lq * 4 + r;
        float v = acc[m][n][r] * dc[m][r] + nz + bv[m][r];
        v = (v > 0.f ? v : 0.2f * v) * 1.4142135623730951f;
        out[(((size_t)b * NCO + co) * 64 + h) * 64 + wcol] = v;
      }
    }
  }
}

extern "C" void kernel_launch(void* const* d_in, const int* in_sizes, int n_in,
                              void* d_out, int out_size, void* d_ws, size_t ws_size,
                              hipStream_t stream) {
  const float* x    = (const float*)d_in[0];
  const float* w    = (const float*)d_in[1];
  const float* aw   = (const float*)d_in[2];
  const float* ab   = (const float*)d_in[3];
  const float* wgt  = (const float*)d_in[4];
  const float* bias = (const float*)d_in[5];
  const float* nc   = (const float*)d_in[6];
  const float* ns   = (const float*)d_in[7];
  float* out = (float*)d_out;

  char* ws = (char*)d_ws;
  float* styles = (float*)(ws);                 // 32 KB
  float* dcoef  = (float*)(ws + 32768);         // 32 KB
  float* wsq    = (float*)(ws + 65536);         // 1 MB
  short* wb2    = (short*)(ws + 1114112);       // 4.5 MB
  short* xt     = (short*)(ws + 5832704);       // 64 MB

  k_styles<<<dim3(16, 16), dim3(256), 0, stream>>>(w, aw, ab, styles);
  k_wt<<<dim3(1024), dim3(256), 0, stream>>>(wgt, wb2, wsq);
  k_dcoef<<<dim3(16, 16), dim3(256), 0, stream>>>(wsq, styles, dcoef);
  k_xt<<<dim3(64, 16, 16), dim3(256), 0, stream>>>(x, styles, xt);
  k_conv<<<dim3(2048), dim3(256), 0, stream>>>(xt, wb2, dcoef, bias, nc, ns, out);
}

// Round 9
// 493.146 us; speedup vs baseline: 1.3245x; 1.0259x over previous
//
#include <hip/hip_runtime.h>

// SynthesisLayer: modulated conv2d 3x3 + demod + noise + bias + lrelu*sqrt(2)
// B=16, CIN=COUT=512, RES=64, WDIM=512

#define NCI  512
#define NCO  512

typedef __attribute__((ext_vector_type(8))) short short8;
typedef __attribute__((ext_vector_type(4))) float f32x4;

#define GLDS16(g, l) __builtin_amdgcn_global_load_lds( \
    (const __attribute__((address_space(1))) void*)(g), \
    (__attribute__((address_space(3))) void*)(l), 16, 0, 0)

static __device__ __forceinline__ unsigned short f2bf(float f) {
  unsigned int u = __float_as_uint(f);
  u += 0x7fffu + ((u >> 16) & 1u);   // RNE
  return (unsigned short)(u >> 16);
}

// ---------------- PK1: styles[b][ci] = m1*m2 + m3 ----------------
__global__ __launch_bounds__(256) void k_styles(
    const float* __restrict__ w, const float* __restrict__ aw,
    const float* __restrict__ ab, float* __restrict__ styles) {
  const int ci0 = blockIdx.x * 32, b = blockIdx.y;
  __shared__ float ws[512];
  __shared__ float pm[3][32];
  const int t = threadIdx.x;
  ws[t] = w[b * 512 + t];
  ws[t + 256] = w[b * 512 + 256 + t];
  __syncthreads();
  const int r = t >> 3, k = t & 7;
#pragma unroll
  for (int pass = 0; pass < 3; ++pass) {
    const float* row = aw + (size_t)(ci0 + r + pass * 512) * 512;
    float a = 0.f;
#pragma unroll 4
    for (int i = 0; i < 16; ++i) {
      float4 v = *(const float4*)(row + i * 32 + k * 4);
      float4 u = *(const float4*)(&ws[i * 32 + k * 4]);
      a += v.x * u.x + v.y * u.y + v.z * u.z + v.w * u.w;
    }
    a += __shfl_xor(a, 1); a += __shfl_xor(a, 2); a += __shfl_xor(a, 4);
    if (k == 0) pm[pass][r] = a;
  }
  __syncthreads();
  if (t < 32) {
    const float g = 0.04419417382415922f;  // 1/sqrt(512)
    int j = ci0 + t;
    float m1 = pm[0][t] * g + ab[j];
    float m2 = pm[1][t] * g + ab[j + 512];
    float m3 = pm[2][t] * g + ab[j + 1024];
    styles[b * 512 + j] = m1 * m2 + m3;
  }
}

// ---------------- PK2: weight -> bf16 fragment-linear wb2 (LDS-tiled), wsq ----------------
// wb2 layout per (ci_blk,co_blk) pair: 18432 shorts = [kk(9)][m(4)][lane(64)][e(8)]
//   lane = ((ci>>3)&3)*16 + (co&15), m=(co>>4)&3, e=ci&7
__global__ __launch_bounds__(256) void k_wt(
    const float* __restrict__ wgt, short* __restrict__ wb2, float* __restrict__ wsq) {
  const int co_blk = blockIdx.x & 7, ci_blk = blockIdx.x >> 3;
  __shared__ short wtile[18432];
  const int t = threadIdx.x;
#pragma unroll
  for (int i = 0; i < 8; ++i) {
    int idx = i * 256 + t;           // 0..2047 = co_l*32 + ci_l
    int co_l = idx >> 5, ci_l = idx & 31;
    int co = co_blk * 64 + co_l, ci = ci_blk * 32 + ci_l;
    const float* p = wgt + ((size_t)co * 512 + ci) * 9;
    int base = (co_l >> 4) * 512 + (((ci_l >> 3) & 3) * 16 + (co_l & 15)) * 8 + (ci_l & 7);
    float s = 0.f;
#pragma unroll
    for (int kk = 0; kk < 9; ++kk) {
      float v = p[kk];
      s += v * v;
      wtile[kk * 2048 + base] = (short)f2bf(v);
    }
    wsq[(size_t)co * 512 + ci] = s;
  }
  __syncthreads();
  short8* dst = (short8*)(wb2 + (size_t)(ci_blk * 8 + co_blk) * 18432);
  const short8* src = (const short8*)wtile;
#pragma unroll
  for (int j = 0; j < 9; ++j) dst[j * 256 + t] = src[j * 256 + t];
}

// ---------------- PK3: dcoef[b][co] = rsqrt(sum_ci wsq*s^2 + 1e-8) ----------------
__global__ __launch_bounds__(256) void k_dcoef(
    const float* __restrict__ wsq, const float* __restrict__ styles,
    float* __restrict__ dcoef) {
  const int co0 = blockIdx.x * 32, b = blockIdx.y;
  __shared__ float ss[512];
  const int t = threadIdx.x;
  float s0 = styles[b * 512 + t], s1 = styles[b * 512 + 256 + t];
  ss[t] = s0 * s0;
  ss[t + 256] = s1 * s1;
  __syncthreads();
  const int r = t >> 3, k = t & 7;
  const float* row = wsq + (size_t)(co0 + r) * 512;
  float a = 0.f;
#pragma unroll 4
  for (int i = 0; i < 16; ++i) {
    float4 v = *(const float4*)(row + i * 32 + k * 4);
    float4 u = *(const float4*)(&ss[i * 32 + k * 4]);
    a += v.x * u.x + v.y * u.y + v.z * u.z + v.w * u.w;
  }
  a += __shfl_xor(a, 1); a += __shfl_xor(a, 2); a += __shfl_xor(a, 4);
  if (k == 0) dcoef[b * 512 + co0 + r] = 1.0f / sqrtf(a + 1e-8f);
}

// ---------------- PK4: xt[b][px][ci] = bf16(x[b][ci][px] * styles[b][ci]) ----------------
// XOR-slot swizzled LDS transpose: write slot pxq^(c&15), read reconstructs.
__global__ __launch_bounds__(256) void k_xt(
    const float* __restrict__ x, const float* __restrict__ styles,
    short* __restrict__ xt) {
  const int px0 = blockIdx.x * 64, ci0 = blockIdx.y * 32, b = blockIdx.z;
  __shared__ float tile[32][68];
  const int t = threadIdx.x;
  {
    const int cil = t >> 4, pxq = t & 15;
#pragma unroll
    for (int half = 0; half < 2; ++half) {
      const int c = cil + half * 16;
      float4 v = *(const float4*)(x + ((size_t)(b * 512 + ci0 + c)) * 4096 + px0 + pxq * 4);
      float sc = styles[b * 512 + ci0 + c];
      v.x *= sc; v.y *= sc; v.z *= sc; v.w *= sc;
      *(float4*)(&tile[c][4 * (pxq ^ (c & 15))]) = v;
    }
  }
  __syncthreads();
  {
    const int pxl = t >> 2, cig = t & 3;
    short8 o;
#pragma unroll
    for (int e = 0; e < 8; ++e) {
      int R = cig * 8 + e;
      o[e] = (short)f2bf(tile[R][4 * ((pxl >> 2) ^ (R & 15)) + (pxl & 3)]);
    }
    *(short8*)(xt + ((size_t)(b * 4096 + px0 + pxl)) * 512 + ci0 + cig * 8) = o;
  }
}

// ---------------- conv: implicit GEMM, 64co x (8 rows x 64 w) per block ----------------
// 4 waves, each wave owns 2 output rows (m=4, n=8). LDS 79.1KB -> 2 blocks/CU.
// xs[10][4][66][8]: 10 input rows (halo top/bottom), k-plane-major, halo cols 0/65 zero.
// wls[9][4][64][8]: fragment-linear W. Both staged via global_load_lds width-16.
__global__ __launch_bounds__(256, 2) void k_conv(
    const short* __restrict__ xt, const short* __restrict__ wb2,
    const float* __restrict__ dcoef, const float* __restrict__ bias,
    const float* __restrict__ noise, const float* __restrict__ nstr,
    float* __restrict__ out) {
  // XCD mapping: bid%8 = XCD = co-block (W slice L2-resident per XCD).
  const int bid = blockIdx.x;          // 1024 blocks = 8co x (16b x 8h)
  const int xcd = bid & 7, i = bid >> 3;
  const int co0 = xcd * 64;
  const int b = i >> 3;
  const int h0 = (i & 7) * 8;

  __shared__ short xs[10][4][66][8];    // 42240 B
  __shared__ short wls[9][4][64][8];    // 36864 B
  const int t = threadIdx.x;
  const int lane = t & 63, wave = t >> 6;
  const int lrow = lane & 15, lq = lane >> 4;

  const short8 z8 = {0, 0, 0, 0, 0, 0, 0, 0};
  // halo columns 0 and 65 of every (r, plane): 10*4*2 = 80 chunks of 16B
  if (t < 80) {
    int r = t / 8, pc = t & 7;
    *(short8*)(&xs[r][pc >> 1][(pc & 1) ? 65 : 0][0]) = z8;
  }
  // out-of-bounds row slabs stay zero for the whole K loop (never staged).
  // slab = 4*66 = 264 short8 chunks > 256 threads -> MUST be a strided loop
  // (R8 bug: `if (t < 264)` left chunks 256..263 uninitialized -> NaN).
  if (h0 == 0) {
    for (int i2 = t; i2 < 264; i2 += 256) ((short8*)&xs[0][0][0][0])[i2] = z8;
  }
  if (h0 == 56) {
    for (int i2 = t; i2 < 264; i2 += 256) ((short8*)&xs[9][0][0][0])[i2] = z8;
  }

  f32x4 acc[4][8];
#pragma unroll
  for (int m = 0; m < 4; ++m)
#pragma unroll
    for (int n = 0; n < 8; ++n)
#pragma unroll
      for (int e = 0; e < 4; ++e) acc[m][n][e] = 0.f;

  const size_t xb = (size_t)b * 4096 * 512;

  for (int cb = 0; cb < 16; ++cb) {
    const int ci0 = cb * 32;
    // ---- stage X: 10 rows x 4 ci-planes = 40 wave-stages ----
#pragma unroll
    for (int i2 = 0; i2 < 10; ++i2) {
      int rp = i2 * 4 + wave;          // 0..39
      int r = rp >> 2, p = rp & 3;
      int row = h0 - 1 + r;
      if ((unsigned)row < 64u) {
        const short* g = xt + xb + ((size_t)(row * 64 + lane)) * 512 + ci0 + p * 8;
        GLDS16(g, &xs[r][p][1][0]);
      }
    }
    // ---- stage W: contiguous 36864B block, 36 wave-stages ----
    const short* wbase = wb2 + (size_t)(cb * 8 + xcd) * 18432;
#pragma unroll
    for (int i2 = 0; i2 < 9; ++i2) {
      int c = i2 * 4 + wave;           // 0..35
      GLDS16(wbase + c * 512 + lane * 8, ((short*)wls) + c * 512);
    }
    __syncthreads();

#pragma unroll
    for (int kh = 0; kh < 3; ++kh) {
#pragma unroll
      for (int kw = 0; kw < 3; ++kw) {
        const int kk = kh * 3 + kw;
        short8 af[4], bf[8];
#pragma unroll
        for (int m = 0; m < 4; ++m)
          af[m] = *(const short8*)(&wls[kk][m][lane][0]);
#pragma unroll
        for (int n = 0; n < 8; ++n)
          bf[n] = *(const short8*)(&xs[2 * wave + kh + (n >> 2)][lq][(n & 3) * 16 + lrow + kw][0]);
#pragma unroll
        for (int m = 0; m < 4; ++m)
#pragma unroll
          for (int n = 0; n < 8; ++n)
            acc[m][n] = __builtin_amdgcn_mfma_f32_16x16x32_bf16(af[m], bf[n], acc[m][n], 0, 0, 0);
      }
    }
    __syncthreads();
  }

  // ---- epilogue: demod, noise, bias, lrelu*sqrt(2) ----
  const float ns = nstr[0];
  float dc[4][4], bv[4][4];
#pragma unroll
  for (int m = 0; m < 4; ++m)
#pragma unroll
    for (int r = 0; r < 4; ++r) {
      int co = co0 + m * 16 + lq * 4 + r;
      dc[m][r] = dcoef[b * NCO + co];
      bv[m][r] = bias[co];
    }
#pragma unroll
  for (int n = 0; n < 8; ++n) {
    int h = h0 + 2 * wave + (n >> 2);
    int wcol = (n & 3) * 16 + lrow;
    float nz = noise[h * 64 + wcol] * ns;
#pragma unroll
    for (int m = 0; m < 4; ++m) {
#pragma unroll
      for (int r = 0; r < 4; ++r) {
        int co = co0 + m * 16 + lq * 4 + r;
        float v = acc[m][n][r] * dc[m][r] + nz + bv[m][r];
        v = (v > 0.f ? v : 0.2f * v) * 1.4142135623730951f;
        out[(((size_t)b * NCO + co) * 64 + h) * 64 + wcol] = v;
      }
    }
  }
}

extern "C" void kernel_launch(void* const* d_in, const int* in_sizes, int n_in,
                              void* d_out, int out_size, void* d_ws, size_t ws_size,
                              hipStream_t stream) {
  const float* x    = (const float*)d_in[0];
  const float* w    = (const float*)d_in[1];
  const float* aw   = (const float*)d_in[2];
  const float* ab   = (const float*)d_in[3];
  const float* wgt  = (const float*)d_in[4];
  const float* bias = (const float*)d_in[5];
  const float* nc   = (const float*)d_in[6];
  const float* ns   = (const float*)d_in[7];
  float* out = (float*)d_out;

  char* ws = (char*)d_ws;
  float* styles = (float*)(ws);                 // 32 KB
  float* dcoef  = (float*)(ws + 32768);         // 32 KB
  float* wsq    = (float*)(ws + 65536);         // 1 MB
  short* wb2    = (short*)(ws + 1114112);       // 4.5 MB
  short* xt     = (short*)(ws + 5832704);       // 64 MB

  k_styles<<<dim3(16, 16), dim3(256), 0, stream>>>(w, aw, ab, styles);
  k_wt<<<dim3(128), dim3(256), 0, stream>>>(wgt, wb2, wsq);
  k_dcoef<<<dim3(16, 16), dim3(256), 0, stream>>>(wsq, styles, dcoef);
  k_xt<<<dim3(64, 16, 16), dim3(256), 0, stream>>>(x, styles, xt);
  k_conv<<<dim3(1024), dim3(256), 0, stream>>>(xt, wb2, dcoef, bias, nc, ns, out);
}

// Round 10
// 487.348 us; speedup vs baseline: 1.3402x; 1.0119x over previous
//
#include <hip/hip_runtime.h>

// SynthesisLayer: modulated conv2d 3x3 + demod + noise + bias + lrelu*sqrt(2)
// B=16, CIN=COUT=512, RES=64, WDIM=512

#define NCI  512
#define NCO  512

typedef __attribute__((ext_vector_type(8))) short short8;
typedef __attribute__((ext_vector_type(4))) float f32x4;

#define GLDS16(g, l) __builtin_amdgcn_global_load_lds( \
    (const __attribute__((address_space(1))) void*)(g), \
    (__attribute__((address_space(3))) void*)(l), 16, 0, 0)

static __device__ __forceinline__ unsigned short f2bf(float f) {
  unsigned int u = __float_as_uint(f);
  u += 0x7fffu + ((u >> 16) & 1u);   // RNE
  return (unsigned short)(u >> 16);
}

// ---------------- PK1: styles[b][ci] = m1*m2 + m3 ----------------
__global__ __launch_bounds__(256) void k_styles(
    const float* __restrict__ w, const float* __restrict__ aw,
    const float* __restrict__ ab, float* __restrict__ styles) {
  const int ci0 = blockIdx.x * 32, b = blockIdx.y;
  __shared__ float ws[512];
  __shared__ float pm[3][32];
  const int t = threadIdx.x;
  ws[t] = w[b * 512 + t];
  ws[t + 256] = w[b * 512 + 256 + t];
  __syncthreads();
  const int r = t >> 3, k = t & 7;
#pragma unroll
  for (int pass = 0; pass < 3; ++pass) {
    const float* row = aw + (size_t)(ci0 + r + pass * 512) * 512;
    float a = 0.f;
#pragma unroll 4
    for (int i = 0; i < 16; ++i) {
      float4 v = *(const float4*)(row + i * 32 + k * 4);
      float4 u = *(const float4*)(&ws[i * 32 + k * 4]);
      a += v.x * u.x + v.y * u.y + v.z * u.z + v.w * u.w;
    }
    a += __shfl_xor(a, 1); a += __shfl_xor(a, 2); a += __shfl_xor(a, 4);
    if (k == 0) pm[pass][r] = a;
  }
  __syncthreads();
  if (t < 32) {
    const float g = 0.04419417382415922f;  // 1/sqrt(512)
    int j = ci0 + t;
    float m1 = pm[0][t] * g + ab[j];
    float m2 = pm[1][t] * g + ab[j + 512];
    float m3 = pm[2][t] * g + ab[j + 1024];
    styles[b * 512 + j] = m1 * m2 + m3;
  }
}

// ---------------- PK2: weight -> bf16 fragment-linear wb2 (LDS-tiled), wsq ----------------
// wb2 layout per (ci_blk,co_blk) pair: 18432 shorts = [kk(9)][m(4)][lane(64)][e(8)]
//   lane = ((ci>>3)&3)*16 + (co&15), m=(co>>4)&3, e=ci&7
__global__ __launch_bounds__(256) void k_wt(
    const float* __restrict__ wgt, short* __restrict__ wb2, float* __restrict__ wsq) {
  const int co_blk = blockIdx.x & 7, ci_blk = blockIdx.x >> 3;
  __shared__ short wtile[18432];
  const int t = threadIdx.x;
#pragma unroll
  for (int i = 0; i < 8; ++i) {
    int idx = i * 256 + t;           // 0..2047 = co_l*32 + ci_l
    int co_l = idx >> 5, ci_l = idx & 31;
    int co = co_blk * 64 + co_l, ci = ci_blk * 32 + ci_l;
    const float* p = wgt + ((size_t)co * 512 + ci) * 9;
    int base = (co_l >> 4) * 512 + (((ci_l >> 3) & 3) * 16 + (co_l & 15)) * 8 + (ci_l & 7);
    float s = 0.f;
#pragma unroll
    for (int kk = 0; kk < 9; ++kk) {
      float v = p[kk];
      s += v * v;
      wtile[kk * 2048 + base] = (short)f2bf(v);
    }
    wsq[(size_t)co * 512 + ci] = s;
  }
  __syncthreads();
  short8* dst = (short8*)(wb2 + (size_t)(ci_blk * 8 + co_blk) * 18432);
  const short8* src = (const short8*)wtile;
#pragma unroll
  for (int j = 0; j < 9; ++j) dst[j * 256 + t] = src[j * 256 + t];
}

// ---------------- PK3: dcoef[b][co] = rsqrt(sum_ci wsq*s^2 + 1e-8) ----------------
__global__ __launch_bounds__(256) void k_dcoef(
    const float* __restrict__ wsq, const float* __restrict__ styles,
    float* __restrict__ dcoef) {
  const int co0 = blockIdx.x * 32, b = blockIdx.y;
  __shared__ float ss[512];
  const int t = threadIdx.x;
  float s0 = styles[b * 512 + t], s1 = styles[b * 512 + 256 + t];
  ss[t] = s0 * s0;
  ss[t + 256] = s1 * s1;
  __syncthreads();
  const int r = t >> 3, k = t & 7;
  const float* row = wsq + (size_t)(co0 + r) * 512;
  float a = 0.f;
#pragma unroll 4
  for (int i = 0; i < 16; ++i) {
    float4 v = *(const float4*)(row + i * 32 + k * 4);
    float4 u = *(const float4*)(&ss[i * 32 + k * 4]);
    a += v.x * u.x + v.y * u.y + v.z * u.z + v.w * u.w;
  }
  a += __shfl_xor(a, 1); a += __shfl_xor(a, 2); a += __shfl_xor(a, 4);
  if (k == 0) dcoef[b * 512 + co0 + r] = 1.0f / sqrtf(a + 1e-8f);
}

// ---------------- PK4: xt[b][px][ci] = bf16(x[b][ci][px] * styles[b][ci]) ----------------
// XOR-slot swizzled LDS transpose: write slot pxq^(c&15), read reconstructs.
__global__ __launch_bounds__(256) void k_xt(
    const float* __restrict__ x, const float* __restrict__ styles,
    short* __restrict__ xt) {
  const int px0 = blockIdx.x * 64, ci0 = blockIdx.y * 32, b = blockIdx.z;
  __shared__ float tile[32][68];
  const int t = threadIdx.x;
  {
    const int cil = t >> 4, pxq = t & 15;
#pragma unroll
    for (int half = 0; half < 2; ++half) {
      const int c = cil + half * 16;
      float4 v = *(const float4*)(x + ((size_t)(b * 512 + ci0 + c)) * 4096 + px0 + pxq * 4);
      float sc = styles[b * 512 + ci0 + c];
      v.x *= sc; v.y *= sc; v.z *= sc; v.w *= sc;
      *(float4*)(&tile[c][4 * (pxq ^ (c & 15))]) = v;
    }
  }
  __syncthreads();
  {
    const int pxl = t >> 2, cig = t & 3;
    short8 o;
#pragma unroll
    for (int e = 0; e < 8; ++e) {
      int R = cig * 8 + e;
      o[e] = (short)f2bf(tile[R][4 * ((pxl >> 2) ^ (R & 15)) + (pxl & 3)]);
    }
    *(short8*)(xt + ((size_t)(b * 4096 + px0 + pxl)) * 512 + ci0 + cig * 8) = o;
  }
}

// ---------------- conv: implicit GEMM, 64co x (8 rows x 64 w) per block ----------------
// 4 waves, each wave owns 2 output rows (m=4, n=8). LDS 79.1KB -> 2 blocks/CU.
// xs[10][4][66][8]: 10 input rows (halo top/bottom), k-plane-major, halo cols 0/65 zero.
// wls[9][4][64][8]: fragment-linear W. Both staged via global_load_lds width-16.
__global__ __launch_bounds__(256, 2) void k_conv(
    const short* __restrict__ xt, const short* __restrict__ wb2,
    const float* __restrict__ dcoef, const float* __restrict__ bias,
    const float* __restrict__ noise, const float* __restrict__ nstr,
    float* __restrict__ out) {
  // XCD mapping v2: the 8 co-blocks of one (b,h0) pair are CONSECUTIVE logicals
  // on ONE XCD (share the x-slab in that XCD's L2); each XCD covers 2 batches.
  // (R9 had co-block=XCD which forced every XCD to re-fetch all of xt: FETCH 339MB.)
  const int bid = blockIdx.x;              // 1024 blocks
  const int logical = (bid & 7) * 128 + (bid >> 3);
  const int coi  = logical & 7;
  const int pair = logical >> 3;           // 0..127 = b*8 + h0blk
  const int b    = pair >> 3;
  const int h0   = (pair & 7) * 8;
  const int co0  = coi * 64;

  __shared__ short xs[10][4][66][8];    // 42240 B
  __shared__ short wls[9][4][64][8];    // 36864 B
  const int t = threadIdx.x;
  const int lane = t & 63, wave = t >> 6;
  const int lrow = lane & 15, lq = lane >> 4;

  const short8 z8 = {0, 0, 0, 0, 0, 0, 0, 0};
  // halo columns 0 and 65 of every (r, plane): 10*4*2 = 80 chunks of 16B
  if (t < 80) {
    int r = t / 8, pc = t & 7;
    *(short8*)(&xs[r][pc >> 1][(pc & 1) ? 65 : 0][0]) = z8;
  }
  // out-of-bounds row slabs stay zero for the whole K loop (never staged).
  // slab = 264 short8 chunks > 256 threads -> strided loop (R8 NaN lesson).
  if (h0 == 0) {
    for (int i2 = t; i2 < 264; i2 += 256) ((short8*)&xs[0][0][0][0])[i2] = z8;
  }
  if (h0 == 56) {
    for (int i2 = t; i2 < 264; i2 += 256) ((short8*)&xs[9][0][0][0])[i2] = z8;
  }

  f32x4 acc[4][8];
#pragma unroll
  for (int m = 0; m < 4; ++m)
#pragma unroll
    for (int n = 0; n < 8; ++n)
#pragma unroll
      for (int e = 0; e < 4; ++e) acc[m][n][e] = 0.f;

  const size_t xb = (size_t)b * 4096 * 512;

  for (int cb = 0; cb < 16; ++cb) {
    const int ci0 = cb * 32;
    // ---- stage X: 10 rows x 4 ci-planes = 40 wave-stages ----
#pragma unroll
    for (int i2 = 0; i2 < 10; ++i2) {
      int rp = i2 * 4 + wave;          // 0..39
      int r = rp >> 2, p = rp & 3;
      int row = h0 - 1 + r;
      if ((unsigned)row < 64u) {
        const short* g = xt + xb + ((size_t)(row * 64 + lane)) * 512 + ci0 + p * 8;
        GLDS16(g, &xs[r][p][1][0]);
      }
    }
    // ---- stage W: contiguous 36864B block, 36 wave-stages ----
    const short* wbase = wb2 + (size_t)(cb * 8 + coi) * 18432;
#pragma unroll
    for (int i2 = 0; i2 < 9; ++i2) {
      int c = i2 * 4 + wave;           // 0..35
      GLDS16(wbase + c * 512 + lane * 8, ((short*)wls) + c * 512);
    }
    __syncthreads();

    // ---- inner: kw-outer with X-fragment register cache ----
    // unique bf addresses per cb = 48 (rows kh+hi overlap); old loop read 72.
#pragma unroll
    for (int kw = 0; kw < 3; ++kw) {
      short8 bx[4][4];
#pragma unroll
      for (int r = 0; r < 4; ++r)
#pragma unroll
        for (int c = 0; c < 4; ++c)
          bx[r][c] = *(const short8*)(&xs[2 * wave + r][lq][c * 16 + lrow + kw][0]);
#pragma unroll
      for (int kh = 0; kh < 3; ++kh) {
        const int kk = kh * 3 + kw;
        short8 af[4];
#pragma unroll
        for (int m = 0; m < 4; ++m)
          af[m] = *(const short8*)(&wls[kk][m][lane][0]);
#pragma unroll
        for (int m = 0; m < 4; ++m)
#pragma unroll
          for (int n = 0; n < 8; ++n)
            acc[m][n] = __builtin_amdgcn_mfma_f32_16x16x32_bf16(
                af[m], bx[kh + (n >> 2)][n & 3], acc[m][n], 0, 0, 0);
      }
    }
    __syncthreads();
  }

  // ---- epilogue: demod, noise, bias, lrelu*sqrt(2) ----
  const float ns = nstr[0];
  float dc[4][4], bv[4][4];
#pragma unroll
  for (int m = 0; m < 4; ++m)
#pragma unroll
    for (int r = 0; r < 4; ++r) {
      int co = co0 + m * 16 + lq * 4 + r;
      dc[m][r] = dcoef[b * NCO + co];
      bv[m][r] = bias[co];
    }
#pragma unroll
  for (int n = 0; n < 8; ++n) {
    int h = h0 + 2 * wave + (n >> 2);
    int wcol = (n & 3) * 16 + lrow;
    float nz = noise[h * 64 + wcol] * ns;
#pragma unroll
    for (int m = 0; m < 4; ++m) {
#pragma unroll
      for (int r = 0; r < 4; ++r) {
        int co = co0 + m * 16 + lq * 4 + r;
        float v = acc[m][n][r] * dc[m][r] + nz + bv[m][r];
        v = (v > 0.f ? v : 0.2f * v) * 1.4142135623730951f;
        out[(((size_t)b * NCO + co) * 64 + h) * 64 + wcol] = v;
      }
    }
  }
}

extern "C" void kernel_launch(void* const* d_in, const int* in_sizes, int n_in,
                              void* d_out, int out_size, void* d_ws, size_t ws_size,
                              hipStream_t stream) {
  const float* x    = (const float*)d_in[0];
  const float* w    = (const float*)d_in[1];
  const float* aw   = (const float*)d_in[2];
  const float* ab   = (const float*)d_in[3];
  const float* wgt  = (const float*)d_in[4];
  const float* bias = (const float*)d_in[5];
  const float* nc   = (const float*)d_in[6];
  const float* ns   = (const float*)d_in[7];
  float* out = (float*)d_out;

  char* ws = (char*)d_ws;
  float* styles = (float*)(ws);                 // 32 KB
  float* dcoef  = (float*)(ws + 32768);         // 32 KB
  float* wsq    = (float*)(ws + 65536);         // 1 MB
  short* wb2    = (short*)(ws + 1114112);       // 4.5 MB
  short* xt     = (short*)(ws + 5832704);       // 64 MB

  k_styles<<<dim3(16, 16), dim3(256), 0, stream>>>(w, aw, ab, styles);
  k_wt<<<dim3(128), dim3(256), 0, stream>>>(wgt, wb2, wsq);
  k_dcoef<<<dim3(16, 16), dim3(256), 0, stream>>>(wsq, styles, dcoef);
  k_xt<<<dim3(64, 16, 16), dim3(256), 0, stream>>>(x, styles, xt);
  k_conv<<<dim3(1024), dim3(256), 0, stream>>>(xt, wb2, dcoef, bias, nc, ns, out);
}